// Round 2
// baseline (333.489 us; speedup 1.0000x reference)
//
#include <hip/hip_runtime.h>
#include <hip/hip_bf16.h>

#define BATCH 32
#define CHN   256
#define HWSZ  1024            // 32*32
#define NPIX  32768           // BATCH*HWSZ
#define NEMB  1024
#define NELEM 8388608         // BATCH*CHN*HWSZ
#define FLT_BIG 3.402823466e+38f

// workspace layout (float offsets)
#define WS_CBT   0            // transposed codebook [256][1024]
#define WS_CNORM 262144       // 1024 floats
#define WS_XNORM 263168       // 32768 floats
#define WS_ACCUM 295936       // 1 double (8B aligned: byte 1183744)

// output layout (float offsets)
#define OUT_U    0
#define OUT_ZT   8388608
#define OUT_LOSS 16777216
#define OUT_IDX  16777217

// ---------------- prep: transpose codebook + code norms ----------------
__global__ __launch_bounds__(256) void k_prep_cb(const float* __restrict__ cb,
                                                 float* __restrict__ ws) {
    int n = blockIdx.x;          // code id 0..1023
    int c = threadIdx.x;         // channel 0..255
    float v = cb[(size_t)n * CHN + c];
    ws[WS_CBT + (size_t)c * NEMB + n] = v;
    float s = v * v;
    #pragma unroll
    for (int off = 32; off > 0; off >>= 1) s += __shfl_down(s, off, 64);
    __shared__ float ls[4];
    int w = threadIdx.x >> 6;
    if ((threadIdx.x & 63) == 0) ls[w] = s;
    __syncthreads();
    if (threadIdx.x == 0) ws[WS_CNORM + n] = (ls[0] + ls[1]) + (ls[2] + ls[3]);
}

// ---------------- prep: pixel norms + zero loss accumulator ----------------
__global__ __launch_bounds__(256) void k_prep_x(const float* __restrict__ u,
                                                float* __restrict__ ws) {
    int P0   = blockIdx.x * 64;       // 512 blocks
    int b    = P0 / HWSZ;
    int hw0  = P0 % HWSZ;
    int lane = threadIdx.x & 63;
    int grp  = threadIdx.x >> 6;      // 0..3 -> channel quarter
    const float* up = u + (size_t)b * CHN * HWSZ + hw0 + lane;
    float s = 0.f;
    int cbase = grp * 64;
    #pragma unroll 8
    for (int c = 0; c < 64; ++c) {
        float v = up[(size_t)(cbase + c) * HWSZ];
        s = fmaf(v, v, s);
    }
    __shared__ float ls[4][64];
    ls[grp][lane] = s;
    __syncthreads();
    if (grp == 0) {
        float x = (ls[0][lane] + ls[1][lane]) + (ls[2][lane] + ls[3][lane]);
        ws[WS_XNORM + P0 + lane] = x;
    }
    if (blockIdx.x == 0 && threadIdx.x == 0)
        *(double*)&ws[WS_ACCUM] = 0.0;
}

// ---------------- main: distance GEMM + argmin ----------------
// 512 blocks x 256 threads. Tile: 64 pixels x 256 codes, 8x8 per thread.
// __launch_bounds__(256,2): grid is only 2 blocks/CU anyway; the 2-waves/EU
// bound gives a 256-VGPR cap so the 64-reg accumulator cannot spill.
__global__ __launch_bounds__(256, 2) void k_argmin(const float* __restrict__ u,
                                                   const float* __restrict__ ws,
                                                   float* __restrict__ out_idx) {
    __shared__ float s_u[32][64];     // [K-chunk][pixel]  8 KB
    __shared__ float s_cb[32][256];   // [K-chunk][code]  32 KB

    const float* cbT   = ws + WS_CBT;
    const float* cnorm = ws + WS_CNORM;
    const float* xnorm = ws + WS_XNORM;

    int T   = blockIdx.x;             // 0..511
    int P0  = T * 64;
    int b   = P0 / HWSZ;
    int hw0 = P0 % HWSZ;
    int tid = threadIdx.x;
    int tx  = tid & 7;                // pixel group (8 pixels each)
    int ty  = tid >> 3;               // 0..31 code group (8 codes each)

    const float* ub = u + (size_t)b * CHN * HWSZ + hw0;

    float xn[8];
    #pragma unroll
    for (int i = 0; i < 8; ++i) xn[i] = xnorm[P0 + tx * 8 + i];

    float dmin[8];
    int   imin[8];
    #pragma unroll
    for (int i = 0; i < 8; ++i) { dmin[i] = FLT_BIG; imin[i] = 0; }

    for (int nt = 0; nt < 4; ++nt) {
        int n0 = nt * 256;
        float acc[8][8];
        #pragma unroll
        for (int i = 0; i < 8; ++i)
            #pragma unroll
            for (int j = 0; j < 8; ++j) acc[i][j] = 0.f;

        for (int kc = 0; kc < 8; ++kc) {
            int c0 = kc * 32;
            __syncthreads();          // protect LDS from readers of prev chunk
            // stage u chunk: 32x64 floats, 2 float4/thread
            #pragma unroll
            for (int it = 0; it < 2; ++it) {
                int q   = it * 256 + tid;
                int k   = q >> 4;
                int pix = (q & 15) << 2;
                float4 v = *(const float4*)&ub[(size_t)(c0 + k) * HWSZ + pix];
                *(float4*)&s_u[k][pix] = v;
            }
            // stage codebook chunk: 32x256 floats, 8 float4/thread
            #pragma unroll
            for (int it = 0; it < 8; ++it) {
                int q = it * 256 + tid;
                int k = q >> 6;
                int j = (q & 63) << 2;
                float4 v = *(const float4*)&cbT[(size_t)(c0 + k) * NEMB + n0 + j];
                *(float4*)&s_cb[k][j] = v;
            }
            __syncthreads();
            #pragma unroll 4
            for (int k = 0; k < 32; ++k) {
                float4 a0 = *(const float4*)&s_u[k][tx * 8];
                float4 a1 = *(const float4*)&s_u[k][tx * 8 + 4];
                float4 b0 = *(const float4*)&s_cb[k][ty * 8];
                float4 b1 = *(const float4*)&s_cb[k][ty * 8 + 4];
                float a[8]; float bb[8];
                a[0]=a0.x; a[1]=a0.y; a[2]=a0.z; a[3]=a0.w;
                a[4]=a1.x; a[5]=a1.y; a[6]=a1.z; a[7]=a1.w;
                bb[0]=b0.x; bb[1]=b0.y; bb[2]=b0.z; bb[3]=b0.w;
                bb[4]=b1.x; bb[5]=b1.y; bb[6]=b1.z; bb[7]=b1.w;
                #pragma unroll
                for (int i = 0; i < 8; ++i)
                    #pragma unroll
                    for (int j = 0; j < 8; ++j)
                        acc[i][j] = fmaf(a[i], bb[j], acc[i][j]);
            }
        }
        // epilogue: distances + running argmin (replicates reference rounding:
        // d = (xnorm - 2*s) + cnorm, two fp32 roundings at the same magnitudes)
        float cn[8];
        #pragma unroll
        for (int j = 0; j < 8; ++j) cn[j] = cnorm[n0 + ty * 8 + j];
        #pragma unroll
        for (int i = 0; i < 8; ++i) {
            #pragma unroll
            for (int j = 0; j < 8; ++j) {
                float t1 = xn[i] - 2.0f * acc[i][j];   // 2*acc exact
                float d  = t1 + cn[j];
                int   n  = n0 + ty * 8 + j;
                if (d < dmin[i]) { dmin[i] = d; imin[i] = n; }  // n increasing per thread
            }
        }
    }

    // cross-thread reduce over the 32 ty groups per pixel (lexicographic (d, n))
    __syncthreads();
    float* red_d = &s_cb[0][0];            // [64][32] floats
    int*   red_i = (int*)&s_cb[8][0];      // [64][32] ints (offset 2048 floats)
    #pragma unroll
    for (int i = 0; i < 8; ++i) {
        red_d[(tx * 8 + i) * 32 + ty] = dmin[i];
        red_i[(tx * 8 + i) * 32 + ty] = imin[i];
    }
    __syncthreads();
    if (tid < 64) {
        float bd = FLT_BIG; int bi = 0x7fffffff;
        #pragma unroll
        for (int t = 0; t < 32; ++t) {
            float d = red_d[tid * 32 + t];
            int   n = red_i[tid * 32 + t];
            if (d < bd || (d == bd && n < bi)) { bd = d; bi = n; }
        }
        out_idx[P0 + tid] = (float)bi;
    }
}

// ---------------- outputs: u copy, z_q gather, loss partial sums ----------------
__global__ __launch_bounds__(256) void k_out(const float* __restrict__ u,
                                             const float* __restrict__ cb,
                                             const float* __restrict__ idxf,
                                             float* __restrict__ out,
                                             double* __restrict__ accum) {
    int P0   = blockIdx.x * 64;       // 512 blocks
    int b    = P0 / HWSZ;
    int hw0  = P0 % HWSZ;
    int lane = threadIdx.x & 63;
    int grp  = threadIdx.x >> 6;      // 0..3
    int p    = P0 + lane;
    int idx  = (int)idxf[p];
    const float* ub    = u + (size_t)b * CHN * HWSZ + hw0 + lane;
    float*       o0    = out + OUT_U  + (size_t)b * CHN * HWSZ + hw0 + lane;
    float*       o1    = out + OUT_ZT + (size_t)b * CHN * HWSZ + hw0 + lane;
    const float* cbrow = cb + (size_t)idx * CHN;
    float s = 0.f;
    #pragma unroll
    for (int r = 0; r < 8; ++r) {
        int c0 = grp * 8 + r * 32;
        float4 z0 = *(const float4*)&cbrow[c0];
        float4 z1 = *(const float4*)&cbrow[c0 + 4];
        float zq[8];
        zq[0]=z0.x; zq[1]=z0.y; zq[2]=z0.z; zq[3]=z0.w;
        zq[4]=z1.x; zq[5]=z1.y; zq[6]=z1.z; zq[7]=z1.w;
        #pragma unroll
        for (int cc = 0; cc < 8; ++cc) {
            int c = c0 + cc;
            float uv = ub[(size_t)c * HWSZ];
            float zv = zq[cc];
            o0[(size_t)c * HWSZ] = uv;
            o1[(size_t)c * HWSZ] = zv;
            float df = zv - uv;
            s = fmaf(df, df, s);
        }
    }
    #pragma unroll
    for (int off = 32; off > 0; off >>= 1) s += __shfl_down(s, off, 64);
    __shared__ float ls[4];
    if (lane == 0) ls[grp] = s;
    __syncthreads();
    if (threadIdx.x == 0) {
        float tot = (ls[0] + ls[1]) + (ls[2] + ls[3]);
        atomicAdd(accum, (double)tot);
    }
}

// ---------------- finalize scalar loss ----------------
__global__ void k_loss(const double* __restrict__ accum,
                       float* __restrict__ out_loss) {
    // reference: codebook_loss + 0.25*commitment_loss, both equal to mean
    float m = (float)(*accum / (double)NELEM);
    out_loss[0] = m + 0.25f * m;
}

extern "C" void kernel_launch(void* const* d_in, const int* in_sizes, int n_in,
                              void* d_out, int out_size, void* d_ws, size_t ws_size,
                              hipStream_t stream) {
    const float* u  = (const float*)d_in[0];
    const float* cb = (const float*)d_in[1];
    float* out = (float*)d_out;
    float* ws  = (float*)d_ws;

    k_prep_cb<<<dim3(NEMB),      dim3(256), 0, stream>>>(cb, ws);
    k_prep_x <<<dim3(NPIX / 64), dim3(256), 0, stream>>>(u, ws);
    k_argmin <<<dim3(NPIX / 64), dim3(256), 0, stream>>>(u, ws, out + OUT_IDX);
    k_out    <<<dim3(NPIX / 64), dim3(256), 0, stream>>>(u, cb, out + OUT_IDX, out,
                                                         (double*)(ws + WS_ACCUM));
    k_loss   <<<dim3(1),         dim3(1),   0, stream>>>((const double*)(ws + WS_ACCUM),
                                                         out + OUT_LOSS);
}

// Round 3
// 326.310 us; speedup vs baseline: 1.0220x; 1.0220x over previous
//
#include <hip/hip_runtime.h>
#include <hip/hip_bf16.h>

#define BATCH 32
#define CHN   256
#define HWSZ  1024            // 32*32
#define NPIX  32768           // BATCH*HWSZ
#define NEMB  1024
#define NELEM 8388608         // BATCH*CHN*HWSZ
#define FLT_BIG 3.402823466e+38f

// workspace layout (float offsets)
#define WS_CBT   0            // transposed codebook [256][1024]
#define WS_CNORM 262144       // 1024 floats
#define WS_XNORM 263168       // 32768 floats
#define WS_ACCUM 295936       // 1 double (8B aligned: byte 1183744)

// output layout (float offsets)
#define OUT_U    0
#define OUT_ZT   8388608
#define OUT_LOSS 16777216
#define OUT_IDX  16777217

// async global->LDS, 16B per lane. LDS dest must be lane-linear (base + lane*16).
__device__ __forceinline__ void gld_lds16(const float* g, float* lds) {
    __builtin_amdgcn_global_load_lds(
        (const __attribute__((address_space(1))) void*)g,
        (__attribute__((address_space(3))) void*)lds, 16, 0, 0);
}

// ---------------- prep: transpose codebook + code norms ----------------
__global__ __launch_bounds__(256) void k_prep_cb(const float* __restrict__ cb,
                                                 float* __restrict__ ws) {
    int n = blockIdx.x;          // code id 0..1023
    int c = threadIdx.x;         // channel 0..255
    float v = cb[(size_t)n * CHN + c];
    ws[WS_CBT + (size_t)c * NEMB + n] = v;
    float s = v * v;
    #pragma unroll
    for (int off = 32; off > 0; off >>= 1) s += __shfl_down(s, off, 64);
    __shared__ float ls[4];
    int w = threadIdx.x >> 6;
    if ((threadIdx.x & 63) == 0) ls[w] = s;
    __syncthreads();
    if (threadIdx.x == 0) ws[WS_CNORM + n] = (ls[0] + ls[1]) + (ls[2] + ls[3]);
}

// ---------------- prep: pixel norms + zero loss accumulator ----------------
__global__ __launch_bounds__(256) void k_prep_x(const float* __restrict__ u,
                                                float* __restrict__ ws) {
    int P0   = blockIdx.x * 64;       // 512 blocks
    int b    = P0 / HWSZ;
    int hw0  = P0 % HWSZ;
    int lane = threadIdx.x & 63;
    int grp  = threadIdx.x >> 6;      // 0..3 -> channel quarter
    const float* up = u + (size_t)b * CHN * HWSZ + hw0 + lane;
    float s = 0.f;
    int cbase = grp * 64;
    #pragma unroll 8
    for (int c = 0; c < 64; ++c) {
        float v = up[(size_t)(cbase + c) * HWSZ];
        s = fmaf(v, v, s);
    }
    __shared__ float ls[4][64];
    ls[grp][lane] = s;
    __syncthreads();
    if (grp == 0) {
        float x = (ls[0][lane] + ls[1][lane]) + (ls[2][lane] + ls[3][lane]);
        ws[WS_XNORM + P0 + lane] = x;
    }
    if (blockIdx.x == 0 && threadIdx.x == 0)
        *(double*)&ws[WS_ACCUM] = 0.0;
}

// ---------------- main: distance GEMM + argmin (double-buffered) ----------------
// 512 blocks x 256 threads. Tile: 64 pixels x 256 codes, 8x8 per thread.
// Pipeline: sync -> issue async loads for chunk s+1 -> compute chunk s.
// The vmcnt(0) drain at each __syncthreads covers loads issued one full
// compute phase earlier -> no stall.
__global__ __launch_bounds__(256, 2) void k_argmin(const float* __restrict__ u,
                                                   const float* __restrict__ ws,
                                                   float* __restrict__ out_idx) {
    __shared__ float s_u[2][32][64];    // 16 KB
    __shared__ float s_cb[2][32][256];  // 64 KB

    const float* cbT   = ws + WS_CBT;
    const float* cnorm = ws + WS_CNORM;
    const float* xnorm = ws + WS_XNORM;

    int T   = blockIdx.x;             // 0..511
    int P0  = T * 64;
    int b   = P0 / HWSZ;
    int hw0 = P0 % HWSZ;
    int tid = threadIdx.x;
    int tx  = tid & 7;                // pixel group (8 pixels each)
    int ty  = tid >> 3;               // 0..31 code group (8 codes each)

    const float* ub = u + (size_t)b * CHN * HWSZ + hw0;

    // precompute per-thread staging indices (chunk-invariant parts)
    int uq0_k  = tid >> 4;            // it=0: k
    int uq0_p  = (tid & 15) << 2;     // it=0: pixel
    int uq1_k  = (256 + tid) >> 4;    // it=1
    int uq1_p  = (tid & 15) << 2;
    int cb_k0  = tid >> 6;            // it adds 4 per step of 256 threads
    int cb_j   = (tid & 63) << 2;

    float xn[8];
    #pragma unroll
    for (int i = 0; i < 8; ++i) xn[i] = xnorm[P0 + tx * 8 + i];

    float dmin[8];
    int   imin[8];
    #pragma unroll
    for (int i = 0; i < 8; ++i) { dmin[i] = FLT_BIG; imin[i] = 0; }

    // ---- staging lambda: chunk s -> buffer buf ----
    auto stage = [&](int s, int buf) {
        int nt = s >> 3;
        int kc = s & 7;
        int n0 = nt * 256;
        int c0 = kc * 32;
        float* su  = &s_u[buf][0][0];
        float* scb = &s_cb[buf][0][0];
        // u chunk: 32x64 floats, 2 16B ops/thread, LDS dest lane-linear
        gld_lds16(&ub[(size_t)(c0 + uq0_k) * HWSZ + uq0_p], &su[tid * 4]);
        gld_lds16(&ub[(size_t)(c0 + uq1_k) * HWSZ + uq1_p], &su[(256 + tid) * 4]);
        // cb chunk: 32x256 floats, 8 16B ops/thread
        #pragma unroll
        for (int it = 0; it < 8; ++it) {
            int k = cb_k0 + it * 4;
            gld_lds16(&cbT[(size_t)(c0 + k) * NEMB + n0 + cb_j],
                      &scb[(it * 256 + tid) * 4]);
        }
    };

    stage(0, 0);

    for (int nt = 0; nt < 4; ++nt) {
        int n0 = nt * 256;
        float acc[8][8];
        #pragma unroll
        for (int i = 0; i < 8; ++i)
            #pragma unroll
            for (int j = 0; j < 8; ++j) acc[i][j] = 0.f;

        for (int kc = 0; kc < 8; ++kc) {
            int s   = nt * 8 + kc;
            int buf = s & 1;
            __syncthreads();              // chunk s resident; all waves off buf^1
            if (s < 31) stage(s + 1, buf ^ 1);
            const float* su  = &s_u[buf][0][0];
            const float* scb = &s_cb[buf][0][0];
            #pragma unroll 8
            for (int k = 0; k < 32; ++k) {
                float4 a0 = *(const float4*)&su[k * 64 + tx * 8];
                float4 a1 = *(const float4*)&su[k * 64 + tx * 8 + 4];
                float4 b0 = *(const float4*)&scb[k * 256 + ty * 8];
                float4 b1 = *(const float4*)&scb[k * 256 + ty * 8 + 4];
                float a[8]; float bb[8];
                a[0]=a0.x; a[1]=a0.y; a[2]=a0.z; a[3]=a0.w;
                a[4]=a1.x; a[5]=a1.y; a[6]=a1.z; a[7]=a1.w;
                bb[0]=b0.x; bb[1]=b0.y; bb[2]=b0.z; bb[3]=b0.w;
                bb[4]=b1.x; bb[5]=b1.y; bb[6]=b1.z; bb[7]=b1.w;
                #pragma unroll
                for (int i = 0; i < 8; ++i)
                    #pragma unroll
                    for (int j = 0; j < 8; ++j)
                        acc[i][j] = fmaf(a[i], bb[j], acc[i][j]);
            }
        }
        // epilogue: distances + running argmin (replicates reference rounding:
        // d = (xnorm - 2*s) + cnorm, two fp32 roundings at the same magnitudes)
        float cn[8];
        #pragma unroll
        for (int j = 0; j < 8; ++j) cn[j] = cnorm[n0 + ty * 8 + j];
        #pragma unroll
        for (int i = 0; i < 8; ++i) {
            #pragma unroll
            for (int j = 0; j < 8; ++j) {
                float t1 = xn[i] - 2.0f * acc[i][j];   // 2*acc exact
                float d  = t1 + cn[j];
                int   n  = n0 + ty * 8 + j;
                if (d < dmin[i]) { dmin[i] = d; imin[i] = n; }  // n increasing per thread
            }
        }
    }

    // cross-thread reduce over the 32 ty groups per pixel (lexicographic (d, n))
    __syncthreads();
    float* red_d = &s_cb[0][0][0];            // [64][32] floats
    int*   red_i = (int*)&s_cb[0][8][0];      // [64][32] ints (2048 floats in)
    #pragma unroll
    for (int i = 0; i < 8; ++i) {
        red_d[(tx * 8 + i) * 32 + ty] = dmin[i];
        red_i[(tx * 8 + i) * 32 + ty] = imin[i];
    }
    __syncthreads();
    if (tid < 64) {
        float bd = FLT_BIG; int bi = 0x7fffffff;
        #pragma unroll
        for (int t = 0; t < 32; ++t) {
            float d = red_d[tid * 32 + t];
            int   n = red_i[tid * 32 + t];
            if (d < bd || (d == bd && n < bi)) { bd = d; bi = n; }
        }
        out_idx[P0 + tid] = (float)bi;
    }
}

// ---------------- outputs: u copy, z_q gather, loss partial sums ----------------
__global__ __launch_bounds__(256) void k_out(const float* __restrict__ u,
                                             const float* __restrict__ cb,
                                             const float* __restrict__ idxf,
                                             float* __restrict__ out,
                                             double* __restrict__ accum) {
    int P0   = blockIdx.x * 64;       // 512 blocks
    int b    = P0 / HWSZ;
    int hw0  = P0 % HWSZ;
    int lane = threadIdx.x & 63;
    int grp  = threadIdx.x >> 6;      // 0..3
    int p    = P0 + lane;
    int idx  = (int)idxf[p];
    const float* ub    = u + (size_t)b * CHN * HWSZ + hw0 + lane;
    float*       o0    = out + OUT_U  + (size_t)b * CHN * HWSZ + hw0 + lane;
    float*       o1    = out + OUT_ZT + (size_t)b * CHN * HWSZ + hw0 + lane;
    const float* cbrow = cb + (size_t)idx * CHN;
    float s = 0.f;
    #pragma unroll
    for (int r = 0; r < 8; ++r) {
        int c0 = grp * 8 + r * 32;
        float4 z0 = *(const float4*)&cbrow[c0];
        float4 z1 = *(const float4*)&cbrow[c0 + 4];
        float zq[8];
        zq[0]=z0.x; zq[1]=z0.y; zq[2]=z0.z; zq[3]=z0.w;
        zq[4]=z1.x; zq[5]=z1.y; zq[6]=z1.z; zq[7]=z1.w;
        #pragma unroll
        for (int cc = 0; cc < 8; ++cc) {
            int c = c0 + cc;
            float uv = ub[(size_t)c * HWSZ];
            float zv = zq[cc];
            o0[(size_t)c * HWSZ] = uv;
            o1[(size_t)c * HWSZ] = zv;
            float df = zv - uv;
            s = fmaf(df, df, s);
        }
    }
    #pragma unroll
    for (int off = 32; off > 0; off >>= 1) s += __shfl_down(s, off, 64);
    __shared__ float ls[4];
    if (lane == 0) ls[grp] = s;
    __syncthreads();
    if (threadIdx.x == 0) {
        float tot = (ls[0] + ls[1]) + (ls[2] + ls[3]);
        atomicAdd(accum, (double)tot);
    }
}

// ---------------- finalize scalar loss ----------------
__global__ void k_loss(const double* __restrict__ accum,
                       float* __restrict__ out_loss) {
    // reference: codebook_loss + 0.25*commitment_loss, both equal to mean
    float m = (float)(*accum / (double)NELEM);
    out_loss[0] = m + 0.25f * m;
}

extern "C" void kernel_launch(void* const* d_in, const int* in_sizes, int n_in,
                              void* d_out, int out_size, void* d_ws, size_t ws_size,
                              hipStream_t stream) {
    const float* u  = (const float*)d_in[0];
    const float* cb = (const float*)d_in[1];
    float* out = (float*)d_out;
    float* ws  = (float*)d_ws;

    k_prep_cb<<<dim3(NEMB),      dim3(256), 0, stream>>>(cb, ws);
    k_prep_x <<<dim3(NPIX / 64), dim3(256), 0, stream>>>(u, ws);
    k_argmin <<<dim3(NPIX / 64), dim3(256), 0, stream>>>(u, ws, out + OUT_IDX);
    k_out    <<<dim3(NPIX / 64), dim3(256), 0, stream>>>(u, cb, out + OUT_IDX, out,
                                                         (double*)(ws + WS_ACCUM));
    k_loss   <<<dim3(1),         dim3(1),   0, stream>>>((const double*)(ws + WS_ACCUM),
                                                         out + OUT_LOSS);
}